// Round 9
// baseline (401.730 us; speedup 1.0000x reference)
//
#include <hip/hip_runtime.h>

#define N_NODES 50000
#define N_EDGES 800000
#define N_META 3
#define IN_DIM 256
#define HD 128
#define HEADS 8
#define HID 16
#define OUT_DIM 8
#define NBKT 196          // ceil(50000/256) coarse buckets; == #4096-edge tiles
#define BCAP 5120         // padded bucket capacity (mean 4096, +16 sigma)
#define TILE_E 4096       // edges per bin block
#define GEMM_BX 391       // grid.x for gemm: 391*16-row tiles, 8 iters/block
#define WG_BX   ((N_NODES + 63) / 64)           // 782 (w_gemm blocks)
#define ELER_BX ((N_NODES * HEADS + 255) / 256) // 1563
#define BING_NB (3 * NBKT)                      // 588 bin blocks (flattened meta)
#define PSTRIDE 132       // per-block partial row: 128 numerator + denom + pad

using bf16x8 = __attribute__((ext_vector_type(8))) short;
using f32x4  = __attribute__((ext_vector_type(4))) float;

__device__ __forceinline__ float bf2f(unsigned short u) {
  union { unsigned int i; float f; } x; x.i = ((unsigned int)u) << 16; return x.f;
}
__device__ __forceinline__ unsigned short f2bf(float f) {
  union { float f; unsigned int i; } x; x.f = f;
  unsigned int r = x.i + 0x7fffu + ((x.i >> 16) & 1u);
  return (unsigned short)(r >> 16);
}
__device__ __forceinline__ float tanh_fast(float x) {
  float e = __expf(2.f * x);
  return 1.f - 2.f / (e + 1.f);
}

// -------- prep: fcw -> fcwT bf16; w1 -> w1T bf16; zero gcur ------------------
__global__ __launch_bounds__(256)
void prep_kernel(const float* __restrict__ fcw, const float* __restrict__ w1,
                 unsigned short* __restrict__ fcwT, unsigned short* __restrict__ w1T,
                 int* __restrict__ gcur) {
  int i = blockIdx.x * 256 + threadIdx.x;
  const int NFC = N_META * IN_DIM * HD;        // 98304
  const int NW1 = HD * HD;                     // 16384
  const int NGC = N_META * NBKT;               // 588
  if (i < NFC) {
    int p = i / (IN_DIM * HD);
    int rem = i - p * (IN_DIM * HD);
    int k = rem / HD, n = rem - k * HD;
    fcwT[(size_t)p * HD * IN_DIM + n * IN_DIM + k] = f2bf(fcw[i]);
  } else if (i < NFC + NW1) {
    int j = i - NFC;
    int k = j / HD, n = j - k * HD;
    w1T[n * HD + k] = f2bf(w1[j]);
  } else if (i < NFC + NW1 + NGC) {
    gcur[i - NFC - NW1] = 0;
  }
}

// ===== bin: padded-bucket counting-sort pass A ===============================
__global__ __launch_bounds__(256)
void bin_kernel(const int* __restrict__ edges, int* __restrict__ gcur,
                unsigned int* __restrict__ bktbuf) {
  __shared__ int hist[NBKT];
  __shared__ int gbase[NBKT];
  __shared__ int fill[NBKT];
  int t = threadIdx.x;
  int bx = blockIdx.x;
  int p = bx / NBKT;
  int b = bx - p * NBKT;
  int e0 = b * TILE_E;
  const int* src = edges + (size_t)p * 2 * N_EDGES;
  const int* dst = src + N_EDGES;
  for (int i = t; i < NBKT; i += 256) { hist[i] = 0; fill[i] = 0; }
  __syncthreads();
  for (int i = t; i < TILE_E; i += 256) {
    int e = e0 + i;
    if (e < N_EDGES) atomicAdd(&hist[dst[e] >> 8], 1);
  }
  __syncthreads();
  for (int i = t; i < NBKT; i += 256) {
    int idx = p * NBKT + i;
    gbase[i] = hist[i] ? (idx * BCAP + atomicAdd(&gcur[idx], hist[i])) : 0;
  }
  __syncthreads();
  for (int i = t; i < TILE_E; i += 256) {
    int e = e0 + i;
    if (e < N_EDGES) {
      int d = dst[e];
      int b2 = d >> 8;
      int r = atomicAdd(&fill[b2], 1);
      bktbuf[gbase[b2] + r] = ((unsigned int)(d & 255) << 16) | (unsigned int)src[e];
    }
  }
}

// ===== feature GEMM (R21): B-in-registers, zero LDS, zero barriers ===========
// R20's B-from-L2-per-kstep serialized the MFMA chain (MfmaUtil 4.6%). Fix:
// per-meta blocks; wave w owns 32 cols, loads its ENTIRE B slice (16 frags =
// 64 VGPR) once at start; the grid-stride row loop then touches memory ONLY
// for the A stream (16 independent float4 loads / 16-row tile, f2bf in-reg)
// and MFMA B operands come from VGPRs with zero latency. All 4 waves read the
// same A rows (L1-hit after first). No LDS, no __syncthreads anywhere.
__global__ __launch_bounds__(256)
void gemm_kernel(const float* __restrict__ A,
                 const unsigned short* __restrict__ BT,
                 unsigned short* __restrict__ Cb, int nrows) {
  int t = threadIdx.x;
  int w = t >> 6, l = t & 63, q = l >> 4, s = l & 15;
  int m = blockIdx.y;
  const unsigned short* Bm = BT + (size_t)m * HD * IN_DIM;
  int c0 = w * 32;                       // wave's 32 output cols within meta m
  bf16x8 bfv[8][2];                      // [kc][nt] : 64 VGPR, loaded once
  #pragma unroll
  for (int kc = 0; kc < 8; ++kc) {
    #pragma unroll
    for (int nt = 0; nt < 2; ++nt)
      bfv[kc][nt] = *(const bf16x8*)(
          Bm + (size_t)(c0 + nt * 16 + s) * IN_DIM + kc * 32 + q * 8);
  }
  unsigned short* Cm = Cb + (size_t)m * N_NODES * HD;
  for (int row0 = blockIdx.x * 16; row0 < nrows; row0 += GEMM_BX * 16) {
    int gr = min(row0 + s, nrows - 1);   // A row for this lane (clamped)
    const float* ap = A + (size_t)gr * IN_DIM + q * 8;
    f32x4 acc[2] = {};
    #pragma unroll
    for (int kc = 0; kc < 8; ++kc) {
      float4 a0 = *(const float4*)(ap + kc * 32);
      float4 a1 = *(const float4*)(ap + kc * 32 + 4);
      union { bf16x8 v; ushort4 u[2]; } cv;
      ushort4 u0, u1;
      u0.x = f2bf(a0.x); u0.y = f2bf(a0.y); u0.z = f2bf(a0.z); u0.w = f2bf(a0.w);
      u1.x = f2bf(a1.x); u1.y = f2bf(a1.y); u1.z = f2bf(a1.z); u1.w = f2bf(a1.w);
      cv.u[0] = u0; cv.u[1] = u1;
      acc[0] = __builtin_amdgcn_mfma_f32_16x16x32_bf16(cv.v, bfv[kc][0], acc[0], 0, 0, 0);
      acc[1] = __builtin_amdgcn_mfma_f32_16x16x32_bf16(cv.v, bfv[kc][1], acc[1], 0, 0, 0);
    }
    #pragma unroll
    for (int nt = 0; nt < 2; ++nt) {
      #pragma unroll
      for (int r = 0; r < 4; ++r) {
        int grow = row0 + q * 4 + r;
        if (grow < nrows) Cm[(size_t)grow * HD + c0 + nt * 16 + s] = f2bf(acc[nt][r]);
      }
    }
  }
}

// ===== Merged dispatch B: csr_sort (x<NBKT) || el_er (x>=NBKT), y = meta =====
__global__ __launch_bounds__(256)
void sort_eler_kernel(const int* __restrict__ gcur,
                      const unsigned int* __restrict__ bktbuf,
                      int* __restrict__ offsB, int* __restrict__ offsE,
                      int* __restrict__ csr,
                      const unsigned short* __restrict__ featb3,
                      const float* __restrict__ al, const float* __restrict__ ar,
                      float* __restrict__ el3, float* __restrict__ er3) {
  __shared__ int lh[256];
  __shared__ int cur[256];
  __shared__ int wsum[4];
  int p = blockIdx.y;
  int t = threadIdx.x;
  if (blockIdx.x < NBKT) {
    // ---- csr_sort body ----
    int b = blockIdx.x;
    int lane = t & 63, wid = t >> 6;
    int idx = p * NBKT + b;
    int S = idx * BCAP;
    int E = S + gcur[idx];
    int node0 = b * 256;
    int nn = min(256, N_NODES - node0);
    int gi0 = p * N_NODES + node0;
    lh[t] = 0;
    __syncthreads();
    for (int i = S + t; i < E; i += 256) atomicAdd(&lh[bktbuf[i] >> 16], 1);
    __syncthreads();
    int v = lh[t];
    int s = v;
    #pragma unroll
    for (int d = 1; d < 64; d <<= 1) {
      int x = __shfl_up(s, d);
      if (lane >= d) s += x;
    }
    if (lane == 63) wsum[wid] = s;
    __syncthreads();
    int woff = 0;
    #pragma unroll
    for (int k = 0; k < 4; ++k) if (k < wid) woff += wsum[k];
    int excl = S + woff + s - v;
    if (t < nn) {
      offsB[gi0 + t] = excl;
      offsE[gi0 + t] = excl + v;
    }
    cur[t] = excl;
    __syncthreads();
    for (int i = S + t; i < E; i += 256) {
      unsigned int rec = bktbuf[i];
      int pos = atomicAdd(&cur[rec >> 16], 1);
      csr[pos] = (int)(rec & 0xffffu);
    }
  } else {
    // ---- el_er body ----
    int i = (blockIdx.x - NBKT) * 256 + t;
    if (i >= N_NODES * HEADS) return;
    int node = i >> 3, hh = i & 7;
    const unsigned short* f =
        featb3 + (size_t)p * N_NODES * HD + (size_t)node * HD + hh * HID;
    uint4 u0 = *(const uint4*)(f);
    uint4 u1 = *(const uint4*)(f + 8);
    unsigned int uu[8] = {u0.x, u0.y, u0.z, u0.w, u1.x, u1.y, u1.z, u1.w};
    const float* alm = al + p * HD + hh * HID;
    const float* arm = ar + p * HD + hh * HID;
    float sl = 0.f, sr = 0.f;
    #pragma unroll
    for (int q = 0; q < 8; ++q) {
      float v0 = __uint_as_float(uu[q] << 16);
      float v1 = __uint_as_float(uu[q] & 0xffff0000u);
      int d = q * 2;
      sl += v0 * alm[d] + v1 * alm[d + 1];
      sr += v0 * arm[d] + v1 * arm[d + 1];
    }
    el3[(size_t)p * N_NODES * HEADS + i] = sl;
    er3[(size_t)p * N_NODES * HEADS + i] = sr;
  }
}

// ------- GAT aggregation (per-meta dispatch; at gather-path roofline) --------
__global__ __launch_bounds__(256)
void aggregate_kernel(const int* __restrict__ offsB3, const int* __restrict__ offsE3,
                      const int* __restrict__ csr,
                      const uint4* __restrict__ featb3_u4,
                      const float* __restrict__ el3, const float* __restrict__ er3,
                      uint4* __restrict__ zb3_u4, int m) {
  int node = blockIdx.x * 4 + (threadIdx.x >> 6);
  if (node >= N_NODES) return;
  const uint4* featb_u4 = featb3_u4 + (size_t)m * N_NODES * 16;
  const float* el = el3 + (size_t)m * N_NODES * HEADS;
  const float* er = er3 + (size_t)m * N_NODES * HEADS;
  uint4* z_u4 = zb3_u4 + (size_t)m * N_NODES * 16;
  int lane = threadIdx.x & 63;
  int qg = lane >> 4;                // edge sub-slot base (0..3)
  int li = lane & 15;                // column quad (cols 8li..8li+7)
  int ch = li >> 1;                  // head of those columns
  int beg = offsB3[m * N_NODES + node], end = offsE3[m * N_NODES + node];
  float erh = er[node * HEADS + ch];
  float ssum = 0.f;
  float a[8] = {};
  for (int i = beg; i < end; i += 16) {
    int nk = end - i;
    int last = end - 1;
    int s0 = csr[min(i + qg,      last)];
    int s1 = csr[min(i + qg + 4,  last)];
    int s2 = csr[min(i + qg + 8,  last)];
    int s3 = csr[min(i + qg + 12, last)];
    uint4 v0 = featb_u4[(size_t)s0 * 16 + li];
    uint4 v1 = featb_u4[(size_t)s1 * 16 + li];
    uint4 v2 = featb_u4[(size_t)s2 * 16 + li];
    uint4 v3 = featb_u4[(size_t)s3 * 16 + li];
    float e0 = el[s0 * HEADS + ch] + erh;
    float e1 = el[s1 * HEADS + ch] + erh;
    float e2 = el[s2 * HEADS + ch] + erh;
    float e3 = el[s3 * HEADS + ch] + erh;
    e0 = e0 > 0.f ? e0 : 0.2f * e0;
    e1 = e1 > 0.f ? e1 : 0.2f * e1;
    e2 = e2 > 0.f ? e2 : 0.2f * e2;
    e3 = e3 > 0.f ? e3 : 0.2f * e3;
    float w0 = (qg      < nk) ? __expf(e0) : 0.f;
    float w1 = (qg + 4  < nk) ? __expf(e1) : 0.f;
    float w2 = (qg + 8  < nk) ? __expf(e2) : 0.f;
    float w3 = (qg + 12 < nk) ? __expf(e3) : 0.f;
    ssum += (w0 + w1) + (w2 + w3);
    a[0] += w0 * __uint_as_float(v0.x << 16);
    a[1] += w0 * __uint_as_float(v0.x & 0xffff0000u);
    a[2] += w0 * __uint_as_float(v0.y << 16);
    a[3] += w0 * __uint_as_float(v0.y & 0xffff0000u);
    a[4] += w0 * __uint_as_float(v0.z << 16);
    a[5] += w0 * __uint_as_float(v0.z & 0xffff0000u);
    a[6] += w0 * __uint_as_float(v0.w << 16);
    a[7] += w0 * __uint_as_float(v0.w & 0xffff0000u);
    a[0] += w1 * __uint_as_float(v1.x << 16);
    a[1] += w1 * __uint_as_float(v1.x & 0xffff0000u);
    a[2] += w1 * __uint_as_float(v1.y << 16);
    a[3] += w1 * __uint_as_float(v1.y & 0xffff0000u);
    a[4] += w1 * __uint_as_float(v1.z << 16);
    a[5] += w1 * __uint_as_float(v1.z & 0xffff0000u);
    a[6] += w1 * __uint_as_float(v1.w << 16);
    a[7] += w1 * __uint_as_float(v1.w & 0xffff0000u);
    a[0] += w2 * __uint_as_float(v2.x << 16);
    a[1] += w2 * __uint_as_float(v2.x & 0xffff0000u);
    a[2] += w2 * __uint_as_float(v2.y << 16);
    a[3] += w2 * __uint_as_float(v2.y & 0xffff0000u);
    a[4] += w2 * __uint_as_float(v2.z << 16);
    a[5] += w2 * __uint_as_float(v2.z & 0xffff0000u);
    a[6] += w2 * __uint_as_float(v2.w << 16);
    a[7] += w2 * __uint_as_float(v2.w & 0xffff0000u);
    a[0] += w3 * __uint_as_float(v3.x << 16);
    a[1] += w3 * __uint_as_float(v3.x & 0xffff0000u);
    a[2] += w3 * __uint_as_float(v3.y << 16);
    a[3] += w3 * __uint_as_float(v3.y & 0xffff0000u);
    a[4] += w3 * __uint_as_float(v3.z << 16);
    a[5] += w3 * __uint_as_float(v3.z & 0xffff0000u);
    a[6] += w3 * __uint_as_float(v3.w << 16);
    a[7] += w3 * __uint_as_float(v3.w & 0xffff0000u);
  }
  #pragma unroll
  for (int j = 0; j < 8; ++j) {
    a[j] += __shfl_xor(a[j], 16);
    a[j] += __shfl_xor(a[j], 32);
  }
  ssum += __shfl_xor(ssum, 16);
  ssum += __shfl_xor(ssum, 32);
  float inv = (end > beg) ? 1.f / ssum : 0.f;
  if (qg == 0) {
    #pragma unroll
    for (int j = 0; j < 8; ++j) {
      float z = a[j] * inv;
      a[j] = z > 0.f ? z : __expf(z) - 1.f;   // fast elu
    }
    uint4 o;
    unsigned int p0, p1, p2, p3;
    asm("v_cvt_pk_bf16_f32 %0, %1, %2" : "=v"(p0) : "v"(a[0]), "v"(a[1]));
    asm("v_cvt_pk_bf16_f32 %0, %1, %2" : "=v"(p1) : "v"(a[2]), "v"(a[3]));
    asm("v_cvt_pk_bf16_f32 %0, %1, %2" : "=v"(p2) : "v"(a[4]), "v"(a[5]));
    asm("v_cvt_pk_bf16_f32 %0, %1, %2" : "=v"(p3) : "v"(a[6]), "v"(a[7]));
    o.x = p0; o.y = p1; o.z = p2; o.w = p3;
    z_u4[(size_t)node * 16 + li] = o;
  }
}

// ------ w_gemm: atomic-free epilogue -> per-block partial rows ---------------
__global__ __launch_bounds__(256)
void w_gemm_mfma(const unsigned short* __restrict__ Zb3,   // [3][N,128] bf16
                 const unsigned short* __restrict__ BT,    // w1T [128][128] bf16
                 const float* __restrict__ B1, const float* __restrict__ W2,
                 float* __restrict__ partial, int nrows) {
  __shared__ unsigned short Bs[128 * 128];   // 32768 B, swizzled 16B chunks
  __shared__ float ew[64];
  __shared__ float part[4][64][2];
  int tid = threadIdx.x;
  int m = blockIdx.y;
  const unsigned short* Zb = Zb3 + (size_t)m * N_NODES * HD;
  int w = tid >> 6, l = tid & 63, q = l >> 4, s = l & 15;
  int row0 = blockIdx.x * 64;
  // stage w1T: chunk j (8 shorts) of row n stored at chunk j^(n&15)
  {
    int n = tid >> 1;
    int jb = (tid & 1) * 8;
    #pragma unroll
    for (int jj = 0; jj < 8; ++jj) {
      int j = jb + jj;
      *(uint4*)&Bs[n * 128 + ((j ^ (n & 15)) << 3)] =
          *(const uint4*)(BT + n * HD + j * 8);
    }
  }
  float b1v[8], w2v[8];
  #pragma unroll
  for (int f = 0; f < 8; ++f) { b1v[f] = B1[f * 16 + s]; w2v[f] = W2[f * 16 + s]; }
  // A fragments direct from global (row clamped; clamped rows' results unused)
  int gra = min(row0 + w * 16 + s, nrows - 1);
  const unsigned short* arow = Zb + (size_t)gra * HD;
  bf16x8 af[4];
  #pragma unroll
  for (int kc = 0; kc < 4; ++kc)
    af[kc] = *(const bf16x8*)(arow + kc * 32 + q * 8);
  __syncthreads();
  f32x4 acc[8] = {};
  #pragma unroll
  for (int kc = 0; kc < 4; ++kc) {
    #pragma unroll
    for (int f = 0; f < 8; ++f) {
      bf16x8 bf = *(bf16x8*)&Bs[(f * 16 + s) * 128 + ((((kc << 2) | q) ^ s) << 3)];
      acc[f] = __builtin_amdgcn_mfma_f32_16x16x32_bf16(af[kc], bf, acc[f], 0, 0, 0);
    }
  }
  // tanh/w2 + s-reduce; lane s==0 writes ew[row] = exp(w-score) (0 if invalid)
  #pragma unroll
  for (int r = 0; r < 4; ++r) {
    float p = 0.f;
    #pragma unroll
    for (int f = 0; f < 8; ++f) p += tanh_fast(acc[f][r] + b1v[f]) * w2v[f];
    p += __shfl_xor(p, 1); p += __shfl_xor(p, 2);
    p += __shfl_xor(p, 4); p += __shfl_xor(p, 8);
    if (s == 0) {
      int rr = w * 16 + q * 4 + r;
      ew[rr] = (row0 + rr < nrows) ? __expf(p) : 0.f;
    }
  }
  __syncthreads();
  // phase 2: numerator cols (2l,2l+1) += ew[r] * z[row0+r][cols], r = w..63(4)
  const unsigned int* Zu = (const unsigned int*)Zb;
  int rmax = min(64, nrows - row0);
  float a0 = 0.f, a1 = 0.f;
  for (int r = w; r < rmax; r += 4) {
    float e = ew[r];
    unsigned int v = Zu[(size_t)(row0 + r) * 64 + l];
    a0 += e * __uint_as_float(v << 16);
    a1 += e * __uint_as_float(v & 0xffff0000u);
  }
  part[w][l][0] = a0;
  part[w][l][1] = a1;
  __syncthreads();
  if (w == 0) {
    float s0 = part[0][l][0] + part[1][l][0] + part[2][l][0] + part[3][l][0];
    float s1 = part[0][l][1] + part[1][l][1] + part[2][l][1] + part[3][l][1];
    float* prow = partial + ((size_t)m * WG_BX + blockIdx.x) * PSTRIDE;
    prow[2 * l]     = s0;
    prow[2 * l + 1] = s1;
    float ldv = ew[l];
    ldv += __shfl_xor(ldv, 1);  ldv += __shfl_xor(ldv, 2);
    ldv += __shfl_xor(ldv, 4);  ldv += __shfl_xor(ldv, 8);
    ldv += __shfl_xor(ldv, 16); ldv += __shfl_xor(ldv, 32);
    if (l == 0) prow[128] = ldv;
  }
}

// ------- reduce partials (782/meta) + final projection -----------------------
__global__ __launch_bounds__(256)
void reduce_final_kernel(const float* __restrict__ partial,
                         const float* __restrict__ PW, const float* __restrict__ PB,
                         float* __restrict__ out) {
  __shared__ float num[129];
  int m = blockIdx.x;
  int t = threadIdx.x;
  if (t < 129) {
    const float* base = partial + (size_t)m * WG_BX * PSTRIDE + t;
    float a0 = 0.f, a1 = 0.f, a2 = 0.f, a3 = 0.f;
    int b = 0;
    for (; b + 4 <= WG_BX; b += 4) {
      a0 += base[(size_t)(b + 0) * PSTRIDE];
      a1 += base[(size_t)(b + 1) * PSTRIDE];
      a2 += base[(size_t)(b + 2) * PSTRIDE];
      a3 += base[(size_t)(b + 3) * PSTRIDE];
    }
    for (; b < WG_BX; ++b) a0 += base[(size_t)b * PSTRIDE];
    num[t] = (a0 + a1) + (a2 + a3);
  }
  __syncthreads();
  if (t < OUT_DIM) {
    float inv = 1.f / num[128];
    float s = 0.f;
    for (int k = 0; k < HD; ++k) s += num[k] * PW[k * OUT_DIM + t];
    out[m * OUT_DIM + t] = s * inv + PB[t];
  }
}

extern "C" void kernel_launch(void* const* d_in, const int* in_sizes, int n_in,
                              void* d_out, int out_size, void* d_ws, size_t ws_size,
                              hipStream_t stream) {
  (void)in_sizes; (void)n_in; (void)out_size; (void)ws_size;
  const float* h     = (const float*)d_in[0];
  const int*   edges = (const int*)d_in[1];
  const float* fcw   = (const float*)d_in[2];
  const float* al    = (const float*)d_in[3];
  const float* ar    = (const float*)d_in[4];
  const float* w1    = (const float*)d_in[5];
  const float* b1    = (const float*)d_in[6];
  const float* w2    = (const float*)d_in[7];
  const float* pw    = (const float*)d_in[8];
  const float* pb    = (const float*)d_in[9];
  float* out = (float*)d_out;

  char* ws = (char*)d_ws;
  size_t off = 0;
  auto alloc = [&](size_t bytes) -> void* {
    void* p = ws + off;
    off = (off + bytes + 255) & ~(size_t)255;
    return p;
  };
  unsigned short* featb3 = (unsigned short*)alloc((size_t)N_META * N_NODES * HD * 2);
  unsigned short* zb3    = (unsigned short*)alloc((size_t)N_META * N_NODES * HD * 2);
  unsigned short* fcwT   = (unsigned short*)alloc((size_t)N_META * HD * IN_DIM * 2);
  unsigned short* w1T    = (unsigned short*)alloc((size_t)HD * HD * 2);
  float* el3 = (float*)alloc((size_t)N_META * N_NODES * HEADS * 4);
  float* er3 = (float*)alloc((size_t)N_META * N_NODES * HEADS * 4);
  int* gcur  = (int*)alloc((size_t)N_META * NBKT * 4);
  int* offsB = (int*)alloc((size_t)N_META * N_NODES * 4);
  int* offsE = (int*)alloc((size_t)N_META * N_NODES * 4);
  unsigned int* bktbuf = (unsigned int*)alloc((size_t)N_META * NBKT * BCAP * 4);
  int* csr   = (int*)alloc((size_t)N_META * NBKT * BCAP * 4);
  float* partial = (float*)alloc((size_t)N_META * WG_BX * PSTRIDE * 4);

  const int PREP_N = N_META * IN_DIM * HD + HD * HD + N_META * NBKT;
  prep_kernel<<<(PREP_N + 255) / 256, 256, 0, stream>>>(
      fcw, w1, fcwT, w1T, gcur);

  // bin and gemm split for per-kernel counters
  bin_kernel<<<BING_NB, 256, 0, stream>>>(edges, gcur, bktbuf);
  dim3 ggrid_(GEMM_BX, N_META);
  gemm_kernel<<<ggrid_, 256, 0, stream>>>(h, fcwT, featb3, N_NODES);

  // B: csr_sort || el_er (independent halves)
  dim3 bgrid_(NBKT + ELER_BX, N_META);
  sort_eler_kernel<<<bgrid_, 256, 0, stream>>>(
      gcur, bktbuf, offsB, offsE, csr, featb3, al, ar, el3, er3);

  // aggregate: one dispatch per meta
  for (int mm = 0; mm < N_META; ++mm) {
    aggregate_kernel<<<(N_NODES + 3) / 4, 256, 0, stream>>>(
        offsB, offsE, csr, (const uint4*)featb3, el3, er3, (uint4*)zb3, mm);
  }

  dim3 wgrid((N_NODES + 63) / 64, N_META);
  w_gemm_mfma<<<wgrid, 256, 0, stream>>>(zb3, w1T, b1, w2, partial, N_NODES);

  reduce_final_kernel<<<N_META, 256, 0, stream>>>(partial, pw, pb, out);
}

// Round 10
// 398.131 us; speedup vs baseline: 1.0090x; 1.0090x over previous
//
#include <hip/hip_runtime.h>

#define N_NODES 50000
#define N_EDGES 800000
#define N_META 3
#define IN_DIM 256
#define HD 128
#define HEADS 8
#define HID 16
#define OUT_DIM 8
#define NBKT 196          // ceil(50000/256) coarse buckets; == #4096-edge tiles
#define BCAP 5120         // padded bucket capacity (mean 4096, +16 sigma)
#define TILE_E 4096       // edges per bin block
#define GEMM_BX 782       // gemm grid.x: 16-row tiles, ~4 grid-stride iters
#define WG_BX   ((N_NODES + 63) / 64)           // 782 (w_gemm blocks)
#define ELER_BX ((N_NODES * HEADS + 255) / 256) // 1563
#define BING_NB (3 * NBKT)                      // 588 bin blocks (flattened meta)
#define PSTRIDE 132       // per-block partial row: 128 numerator + denom + pad

using bf16x8 = __attribute__((ext_vector_type(8))) short;
using f32x4  = __attribute__((ext_vector_type(4))) float;

__device__ __forceinline__ float bf2f(unsigned short u) {
  union { unsigned int i; float f; } x; x.i = ((unsigned int)u) << 16; return x.f;
}
__device__ __forceinline__ unsigned short f2bf(float f) {
  union { float f; unsigned int i; } x; x.f = f;
  unsigned int r = x.i + 0x7fffu + ((x.i >> 16) & 1u);
  return (unsigned short)(r >> 16);
}
__device__ __forceinline__ float tanh_fast(float x) {
  float e = __expf(2.f * x);
  return 1.f - 2.f / (e + 1.f);
}

// -------- prep: fcw -> fcwT bf16; w1 -> w1T bf16; zero gcur ------------------
__global__ __launch_bounds__(256)
void prep_kernel(const float* __restrict__ fcw, const float* __restrict__ w1,
                 unsigned short* __restrict__ fcwT, unsigned short* __restrict__ w1T,
                 int* __restrict__ gcur) {
  int i = blockIdx.x * 256 + threadIdx.x;
  const int NFC = N_META * IN_DIM * HD;        // 98304
  const int NW1 = HD * HD;                     // 16384
  const int NGC = N_META * NBKT;               // 588
  if (i < NFC) {
    int p = i / (IN_DIM * HD);
    int rem = i - p * (IN_DIM * HD);
    int k = rem / HD, n = rem - k * HD;
    fcwT[(size_t)p * HD * IN_DIM + n * IN_DIM + k] = f2bf(fcw[i]);
  } else if (i < NFC + NW1) {
    int j = i - NFC;
    int k = j / HD, n = j - k * HD;
    w1T[n * HD + k] = f2bf(w1[j]);
  } else if (i < NFC + NW1 + NGC) {
    gcur[i - NFC - NW1] = 0;
  }
}

// ===== bin: padded-bucket counting-sort pass A ===============================
__global__ __launch_bounds__(256)
void bin_kernel(const int* __restrict__ edges, int* __restrict__ gcur,
                unsigned int* __restrict__ bktbuf) {
  __shared__ int hist[NBKT];
  __shared__ int gbase[NBKT];
  __shared__ int fill[NBKT];
  int t = threadIdx.x;
  int bx = blockIdx.x;
  int p = bx / NBKT;
  int b = bx - p * NBKT;
  int e0 = b * TILE_E;
  const int* src = edges + (size_t)p * 2 * N_EDGES;
  const int* dst = src + N_EDGES;
  for (int i = t; i < NBKT; i += 256) { hist[i] = 0; fill[i] = 0; }
  __syncthreads();
  for (int i = t; i < TILE_E; i += 256) {
    int e = e0 + i;
    if (e < N_EDGES) atomicAdd(&hist[dst[e] >> 8], 1);
  }
  __syncthreads();
  for (int i = t; i < NBKT; i += 256) {
    int idx = p * NBKT + i;
    gbase[i] = hist[i] ? (idx * BCAP + atomicAdd(&gcur[idx], hist[i])) : 0;
  }
  __syncthreads();
  for (int i = t; i < TILE_E; i += 256) {
    int e = e0 + i;
    if (e < N_EDGES) {
      int d = dst[e];
      int b2 = d >> 8;
      int r = atomicAdd(&fill[b2], 1);
      bktbuf[gbase[b2] + r] = ((unsigned int)(d & 255) << 16) | (unsigned int)src[e];
    }
  }
}

// ===== feature GEMM (R22): 8 waves, B-in-regs, A read ONCE, no LDS/barriers ==
// Constraint set from R19-R21: (1) A streamed once per block for ALL 3 metas
// [R21 violated: FETCH 3x], (2) B operands out of the k-loop's memory path
// [R20 violated: L2-latency-serialized MFMA], (3) no per-k-step barriers
// [R19 violated]. 512 threads = 8 waves; wave w owns 48 of 384 concat cols,
// preloads its B-slice (24 frags = 96 VGPR) once; grid-stride 16-row tiles:
// 16 indep A-loads (same rows for all 8 waves -> L1 broadcast) + 24 reg-B
// MFMAs per tile.
__global__ __launch_bounds__(512)
void gemm_kernel(const float* __restrict__ A,
                 const unsigned short* __restrict__ BT,
                 unsigned short* __restrict__ Cb, int nrows) {
  int t = threadIdx.x;
  int w = t >> 6, l = t & 63, q = l >> 4, s = l & 15;
  int c0 = w * 48;                       // wave's 48 cols within 384 concat
  bf16x8 bfv[8][3];                      // [kc][nt] : 96 VGPR, loaded once
  #pragma unroll
  for (int kc = 0; kc < 8; ++kc) {
    #pragma unroll
    for (int nt = 0; nt < 3; ++nt) {
      int gc = c0 + nt * 16 + s;
      int mm = gc >> 7, cim = gc & 127;
      bfv[kc][nt] = *(const bf16x8*)(
          BT + ((size_t)mm * HD + cim) * IN_DIM + kc * 32 + q * 8);
    }
  }
  for (int row0 = blockIdx.x * 16; row0 < nrows; row0 += GEMM_BX * 16) {
    int gr = min(row0 + s, nrows - 1);   // A row for this lane (clamped)
    const float* ap = A + (size_t)gr * IN_DIM + q * 8;
    f32x4 acc[3] = {};
    #pragma unroll
    for (int kc = 0; kc < 8; ++kc) {
      float4 a0 = *(const float4*)(ap + kc * 32);
      float4 a1 = *(const float4*)(ap + kc * 32 + 4);
      union { bf16x8 v; ushort4 u[2]; } cv;
      ushort4 u0, u1;
      u0.x = f2bf(a0.x); u0.y = f2bf(a0.y); u0.z = f2bf(a0.z); u0.w = f2bf(a0.w);
      u1.x = f2bf(a1.x); u1.y = f2bf(a1.y); u1.z = f2bf(a1.z); u1.w = f2bf(a1.w);
      cv.u[0] = u0; cv.u[1] = u1;
      acc[0] = __builtin_amdgcn_mfma_f32_16x16x32_bf16(cv.v, bfv[kc][0], acc[0], 0, 0, 0);
      acc[1] = __builtin_amdgcn_mfma_f32_16x16x32_bf16(cv.v, bfv[kc][1], acc[1], 0, 0, 0);
      acc[2] = __builtin_amdgcn_mfma_f32_16x16x32_bf16(cv.v, bfv[kc][2], acc[2], 0, 0, 0);
    }
    #pragma unroll
    for (int nt = 0; nt < 3; ++nt) {
      int gc = c0 + nt * 16 + s;
      int mm = gc >> 7, cim = gc & 127;
      unsigned short* Cm = Cb + (size_t)mm * N_NODES * HD;
      #pragma unroll
      for (int r = 0; r < 4; ++r) {
        int grow = row0 + q * 4 + r;
        if (grow < nrows) Cm[(size_t)grow * HD + cim] = f2bf(acc[nt][r]);
      }
    }
  }
}

// ===== Merged dispatch B: csr_sort (x<NBKT) || el_er (x>=NBKT), y = meta =====
__global__ __launch_bounds__(256)
void sort_eler_kernel(const int* __restrict__ gcur,
                      const unsigned int* __restrict__ bktbuf,
                      int* __restrict__ offsB, int* __restrict__ offsE,
                      int* __restrict__ csr,
                      const unsigned short* __restrict__ featb3,
                      const float* __restrict__ al, const float* __restrict__ ar,
                      float* __restrict__ el3, float* __restrict__ er3) {
  __shared__ int lh[256];
  __shared__ int cur[256];
  __shared__ int wsum[4];
  int p = blockIdx.y;
  int t = threadIdx.x;
  if (blockIdx.x < NBKT) {
    // ---- csr_sort body ----
    int b = blockIdx.x;
    int lane = t & 63, wid = t >> 6;
    int idx = p * NBKT + b;
    int S = idx * BCAP;
    int E = S + gcur[idx];
    int node0 = b * 256;
    int nn = min(256, N_NODES - node0);
    int gi0 = p * N_NODES + node0;
    lh[t] = 0;
    __syncthreads();
    for (int i = S + t; i < E; i += 256) atomicAdd(&lh[bktbuf[i] >> 16], 1);
    __syncthreads();
    int v = lh[t];
    int s = v;
    #pragma unroll
    for (int d = 1; d < 64; d <<= 1) {
      int x = __shfl_up(s, d);
      if (lane >= d) s += x;
    }
    if (lane == 63) wsum[wid] = s;
    __syncthreads();
    int woff = 0;
    #pragma unroll
    for (int k = 0; k < 4; ++k) if (k < wid) woff += wsum[k];
    int excl = S + woff + s - v;
    if (t < nn) {
      offsB[gi0 + t] = excl;
      offsE[gi0 + t] = excl + v;
    }
    cur[t] = excl;
    __syncthreads();
    for (int i = S + t; i < E; i += 256) {
      unsigned int rec = bktbuf[i];
      int pos = atomicAdd(&cur[rec >> 16], 1);
      csr[pos] = (int)(rec & 0xffffu);
    }
  } else {
    // ---- el_er body ----
    int i = (blockIdx.x - NBKT) * 256 + t;
    if (i >= N_NODES * HEADS) return;
    int node = i >> 3, hh = i & 7;
    const unsigned short* f =
        featb3 + (size_t)p * N_NODES * HD + (size_t)node * HD + hh * HID;
    uint4 u0 = *(const uint4*)(f);
    uint4 u1 = *(const uint4*)(f + 8);
    unsigned int uu[8] = {u0.x, u0.y, u0.z, u0.w, u1.x, u1.y, u1.z, u1.w};
    const float* alm = al + p * HD + hh * HID;
    const float* arm = ar + p * HD + hh * HID;
    float sl = 0.f, sr = 0.f;
    #pragma unroll
    for (int q = 0; q < 8; ++q) {
      float v0 = __uint_as_float(uu[q] << 16);
      float v1 = __uint_as_float(uu[q] & 0xffff0000u);
      int d = q * 2;
      sl += v0 * alm[d] + v1 * alm[d + 1];
      sr += v0 * arm[d] + v1 * arm[d + 1];
    }
    el3[(size_t)p * N_NODES * HEADS + i] = sl;
    er3[(size_t)p * N_NODES * HEADS + i] = sr;
  }
}

// ------- GAT aggregation (per-meta dispatch; at gather-path roofline) --------
__global__ __launch_bounds__(256)
void aggregate_kernel(const int* __restrict__ offsB3, const int* __restrict__ offsE3,
                      const int* __restrict__ csr,
                      const uint4* __restrict__ featb3_u4,
                      const float* __restrict__ el3, const float* __restrict__ er3,
                      uint4* __restrict__ zb3_u4, int m) {
  int node = blockIdx.x * 4 + (threadIdx.x >> 6);
  if (node >= N_NODES) return;
  const uint4* featb_u4 = featb3_u4 + (size_t)m * N_NODES * 16;
  const float* el = el3 + (size_t)m * N_NODES * HEADS;
  const float* er = er3 + (size_t)m * N_NODES * HEADS;
  uint4* z_u4 = zb3_u4 + (size_t)m * N_NODES * 16;
  int lane = threadIdx.x & 63;
  int qg = lane >> 4;                // edge sub-slot base (0..3)
  int li = lane & 15;                // column quad (cols 8li..8li+7)
  int ch = li >> 1;                  // head of those columns
  int beg = offsB3[m * N_NODES + node], end = offsE3[m * N_NODES + node];
  float erh = er[node * HEADS + ch];
  float ssum = 0.f;
  float a[8] = {};
  for (int i = beg; i < end; i += 16) {
    int nk = end - i;
    int last = end - 1;
    int s0 = csr[min(i + qg,      last)];
    int s1 = csr[min(i + qg + 4,  last)];
    int s2 = csr[min(i + qg + 8,  last)];
    int s3 = csr[min(i + qg + 12, last)];
    uint4 v0 = featb_u4[(size_t)s0 * 16 + li];
    uint4 v1 = featb_u4[(size_t)s1 * 16 + li];
    uint4 v2 = featb_u4[(size_t)s2 * 16 + li];
    uint4 v3 = featb_u4[(size_t)s3 * 16 + li];
    float e0 = el[s0 * HEADS + ch] + erh;
    float e1 = el[s1 * HEADS + ch] + erh;
    float e2 = el[s2 * HEADS + ch] + erh;
    float e3 = el[s3 * HEADS + ch] + erh;
    e0 = e0 > 0.f ? e0 : 0.2f * e0;
    e1 = e1 > 0.f ? e1 : 0.2f * e1;
    e2 = e2 > 0.f ? e2 : 0.2f * e2;
    e3 = e3 > 0.f ? e3 : 0.2f * e3;
    float w0 = (qg      < nk) ? __expf(e0) : 0.f;
    float w1 = (qg + 4  < nk) ? __expf(e1) : 0.f;
    float w2 = (qg + 8  < nk) ? __expf(e2) : 0.f;
    float w3 = (qg + 12 < nk) ? __expf(e3) : 0.f;
    ssum += (w0 + w1) + (w2 + w3);
    a[0] += w0 * __uint_as_float(v0.x << 16);
    a[1] += w0 * __uint_as_float(v0.x & 0xffff0000u);
    a[2] += w0 * __uint_as_float(v0.y << 16);
    a[3] += w0 * __uint_as_float(v0.y & 0xffff0000u);
    a[4] += w0 * __uint_as_float(v0.z << 16);
    a[5] += w0 * __uint_as_float(v0.z & 0xffff0000u);
    a[6] += w0 * __uint_as_float(v0.w << 16);
    a[7] += w0 * __uint_as_float(v0.w & 0xffff0000u);
    a[0] += w1 * __uint_as_float(v1.x << 16);
    a[1] += w1 * __uint_as_float(v1.x & 0xffff0000u);
    a[2] += w1 * __uint_as_float(v1.y << 16);
    a[3] += w1 * __uint_as_float(v1.y & 0xffff0000u);
    a[4] += w1 * __uint_as_float(v1.z << 16);
    a[5] += w1 * __uint_as_float(v1.z & 0xffff0000u);
    a[6] += w1 * __uint_as_float(v1.w << 16);
    a[7] += w1 * __uint_as_float(v1.w & 0xffff0000u);
    a[0] += w2 * __uint_as_float(v2.x << 16);
    a[1] += w2 * __uint_as_float(v2.x & 0xffff0000u);
    a[2] += w2 * __uint_as_float(v2.y << 16);
    a[3] += w2 * __uint_as_float(v2.y & 0xffff0000u);
    a[4] += w2 * __uint_as_float(v2.z << 16);
    a[5] += w2 * __uint_as_float(v2.z & 0xffff0000u);
    a[6] += w2 * __uint_as_float(v2.w << 16);
    a[7] += w2 * __uint_as_float(v2.w & 0xffff0000u);
    a[0] += w3 * __uint_as_float(v3.x << 16);
    a[1] += w3 * __uint_as_float(v3.x & 0xffff0000u);
    a[2] += w3 * __uint_as_float(v3.y << 16);
    a[3] += w3 * __uint_as_float(v3.y & 0xffff0000u);
    a[4] += w3 * __uint_as_float(v3.z << 16);
    a[5] += w3 * __uint_as_float(v3.z & 0xffff0000u);
    a[6] += w3 * __uint_as_float(v3.w << 16);
    a[7] += w3 * __uint_as_float(v3.w & 0xffff0000u);
  }
  #pragma unroll
  for (int j = 0; j < 8; ++j) {
    a[j] += __shfl_xor(a[j], 16);
    a[j] += __shfl_xor(a[j], 32);
  }
  ssum += __shfl_xor(ssum, 16);
  ssum += __shfl_xor(ssum, 32);
  float inv = (end > beg) ? 1.f / ssum : 0.f;
  if (qg == 0) {
    #pragma unroll
    for (int j = 0; j < 8; ++j) {
      float z = a[j] * inv;
      a[j] = z > 0.f ? z : __expf(z) - 1.f;   // fast elu
    }
    uint4 o;
    unsigned int p0, p1, p2, p3;
    asm("v_cvt_pk_bf16_f32 %0, %1, %2" : "=v"(p0) : "v"(a[0]), "v"(a[1]));
    asm("v_cvt_pk_bf16_f32 %0, %1, %2" : "=v"(p1) : "v"(a[2]), "v"(a[3]));
    asm("v_cvt_pk_bf16_f32 %0, %1, %2" : "=v"(p2) : "v"(a[4]), "v"(a[5]));
    asm("v_cvt_pk_bf16_f32 %0, %1, %2" : "=v"(p3) : "v"(a[6]), "v"(a[7]));
    o.x = p0; o.y = p1; o.z = p2; o.w = p3;
    z_u4[(size_t)node * 16 + li] = o;
  }
}

// ------ w_gemm: atomic-free epilogue -> per-block partial rows ---------------
__global__ __launch_bounds__(256)
void w_gemm_mfma(const unsigned short* __restrict__ Zb3,   // [3][N,128] bf16
                 const unsigned short* __restrict__ BT,    // w1T [128][128] bf16
                 const float* __restrict__ B1, const float* __restrict__ W2,
                 float* __restrict__ partial, int nrows) {
  __shared__ unsigned short Bs[128 * 128];   // 32768 B, swizzled 16B chunks
  __shared__ float ew[64];
  __shared__ float part[4][64][2];
  int tid = threadIdx.x;
  int m = blockIdx.y;
  const unsigned short* Zb = Zb3 + (size_t)m * N_NODES * HD;
  int w = tid >> 6, l = tid & 63, q = l >> 4, s = l & 15;
  int row0 = blockIdx.x * 64;
  // stage w1T: chunk j (8 shorts) of row n stored at chunk j^(n&15)
  {
    int n = tid >> 1;
    int jb = (tid & 1) * 8;
    #pragma unroll
    for (int jj = 0; jj < 8; ++jj) {
      int j = jb + jj;
      *(uint4*)&Bs[n * 128 + ((j ^ (n & 15)) << 3)] =
          *(const uint4*)(BT + n * HD + j * 8);
    }
  }
  float b1v[8], w2v[8];
  #pragma unroll
  for (int f = 0; f < 8; ++f) { b1v[f] = B1[f * 16 + s]; w2v[f] = W2[f * 16 + s]; }
  // A fragments direct from global (row clamped; clamped rows' results unused)
  int gra = min(row0 + w * 16 + s, nrows - 1);
  const unsigned short* arow = Zb + (size_t)gra * HD;
  bf16x8 af[4];
  #pragma unroll
  for (int kc = 0; kc < 4; ++kc)
    af[kc] = *(const bf16x8*)(arow + kc * 32 + q * 8);
  __syncthreads();
  f32x4 acc[8] = {};
  #pragma unroll
  for (int kc = 0; kc < 4; ++kc) {
    #pragma unroll
    for (int f = 0; f < 8; ++f) {
      bf16x8 bf = *(bf16x8*)&Bs[(f * 16 + s) * 128 + ((((kc << 2) | q) ^ s) << 3)];
      acc[f] = __builtin_amdgcn_mfma_f32_16x16x32_bf16(af[kc], bf, acc[f], 0, 0, 0);
    }
  }
  // tanh/w2 + s-reduce; lane s==0 writes ew[row] = exp(w-score) (0 if invalid)
  #pragma unroll
  for (int r = 0; r < 4; ++r) {
    float p = 0.f;
    #pragma unroll
    for (int f = 0; f < 8; ++f) p += tanh_fast(acc[f][r] + b1v[f]) * w2v[f];
    p += __shfl_xor(p, 1); p += __shfl_xor(p, 2);
    p += __shfl_xor(p, 4); p += __shfl_xor(p, 8);
    if (s == 0) {
      int rr = w * 16 + q * 4 + r;
      ew[rr] = (row0 + rr < nrows) ? __expf(p) : 0.f;
    }
  }
  __syncthreads();
  // phase 2: numerator cols (2l,2l+1) += ew[r] * z[row0+r][cols], r = w..63(4)
  const unsigned int* Zu = (const unsigned int*)Zb;
  int rmax = min(64, nrows - row0);
  float a0 = 0.f, a1 = 0.f;
  for (int r = w; r < rmax; r += 4) {
    float e = ew[r];
    unsigned int v = Zu[(size_t)(row0 + r) * 64 + l];
    a0 += e * __uint_as_float(v << 16);
    a1 += e * __uint_as_float(v & 0xffff0000u);
  }
  part[w][l][0] = a0;
  part[w][l][1] = a1;
  __syncthreads();
  if (w == 0) {
    float s0 = part[0][l][0] + part[1][l][0] + part[2][l][0] + part[3][l][0];
    float s1 = part[0][l][1] + part[1][l][1] + part[2][l][1] + part[3][l][1];
    float* prow = partial + ((size_t)m * WG_BX + blockIdx.x) * PSTRIDE;
    prow[2 * l]     = s0;
    prow[2 * l + 1] = s1;
    float ldv = ew[l];
    ldv += __shfl_xor(ldv, 1);  ldv += __shfl_xor(ldv, 2);
    ldv += __shfl_xor(ldv, 4);  ldv += __shfl_xor(ldv, 8);
    ldv += __shfl_xor(ldv, 16); ldv += __shfl_xor(ldv, 32);
    if (l == 0) prow[128] = ldv;
  }
}

// ------- reduce partials (782/meta) + final projection -----------------------
__global__ __launch_bounds__(256)
void reduce_final_kernel(const float* __restrict__ partial,
                         const float* __restrict__ PW, const float* __restrict__ PB,
                         float* __restrict__ out) {
  __shared__ float num[129];
  int m = blockIdx.x;
  int t = threadIdx.x;
  if (t < 129) {
    const float* base = partial + (size_t)m * WG_BX * PSTRIDE + t;
    float a0 = 0.f, a1 = 0.f, a2 = 0.f, a3 = 0.f;
    int b = 0;
    for (; b + 4 <= WG_BX; b += 4) {
      a0 += base[(size_t)(b + 0) * PSTRIDE];
      a1 += base[(size_t)(b + 1) * PSTRIDE];
      a2 += base[(size_t)(b + 2) * PSTRIDE];
      a3 += base[(size_t)(b + 3) * PSTRIDE];
    }
    for (; b < WG_BX; ++b) a0 += base[(size_t)b * PSTRIDE];
    num[t] = (a0 + a1) + (a2 + a3);
  }
  __syncthreads();
  if (t < OUT_DIM) {
    float inv = 1.f / num[128];
    float s = 0.f;
    for (int k = 0; k < HD; ++k) s += num[k] * PW[k * OUT_DIM + t];
    out[m * OUT_DIM + t] = s * inv + PB[t];
  }
}

extern "C" void kernel_launch(void* const* d_in, const int* in_sizes, int n_in,
                              void* d_out, int out_size, void* d_ws, size_t ws_size,
                              hipStream_t stream) {
  (void)in_sizes; (void)n_in; (void)out_size; (void)ws_size;
  const float* h     = (const float*)d_in[0];
  const int*   edges = (const int*)d_in[1];
  const float* fcw   = (const float*)d_in[2];
  const float* al    = (const float*)d_in[3];
  const float* ar    = (const float*)d_in[4];
  const float* w1    = (const float*)d_in[5];
  const float* b1    = (const float*)d_in[6];
  const float* w2    = (const float*)d_in[7];
  const float* pw    = (const float*)d_in[8];
  const float* pb    = (const float*)d_in[9];
  float* out = (float*)d_out;

  char* ws = (char*)d_ws;
  size_t off = 0;
  auto alloc = [&](size_t bytes) -> void* {
    void* p = ws + off;
    off = (off + bytes + 255) & ~(size_t)255;
    return p;
  };
  unsigned short* featb3 = (unsigned short*)alloc((size_t)N_META * N_NODES * HD * 2);
  unsigned short* zb3    = (unsigned short*)alloc((size_t)N_META * N_NODES * HD * 2);
  unsigned short* fcwT   = (unsigned short*)alloc((size_t)N_META * HD * IN_DIM * 2);
  unsigned short* w1T    = (unsigned short*)alloc((size_t)HD * HD * 2);
  float* el3 = (float*)alloc((size_t)N_META * N_NODES * HEADS * 4);
  float* er3 = (float*)alloc((size_t)N_META * N_NODES * HEADS * 4);
  int* gcur  = (int*)alloc((size_t)N_META * NBKT * 4);
  int* offsB = (int*)alloc((size_t)N_META * N_NODES * 4);
  int* offsE = (int*)alloc((size_t)N_META * N_NODES * 4);
  unsigned int* bktbuf = (unsigned int*)alloc((size_t)N_META * NBKT * BCAP * 4);
  int* csr   = (int*)alloc((size_t)N_META * NBKT * BCAP * 4);
  float* partial = (float*)alloc((size_t)N_META * WG_BX * PSTRIDE * 4);

  const int PREP_N = N_META * IN_DIM * HD + HD * HD + N_META * NBKT;
  prep_kernel<<<(PREP_N + 255) / 256, 256, 0, stream>>>(
      fcw, w1, fcwT, w1T, gcur);

  // bin and gemm split for per-kernel counters
  bin_kernel<<<BING_NB, 256, 0, stream>>>(edges, gcur, bktbuf);
  gemm_kernel<<<GEMM_BX, 512, 0, stream>>>(h, fcwT, featb3, N_NODES);

  // B: csr_sort || el_er (independent halves)
  dim3 bgrid_(NBKT + ELER_BX, N_META);
  sort_eler_kernel<<<bgrid_, 256, 0, stream>>>(
      gcur, bktbuf, offsB, offsE, csr, featb3, al, ar, el3, er3);

  // aggregate: one dispatch per meta
  for (int mm = 0; mm < N_META; ++mm) {
    aggregate_kernel<<<(N_NODES + 3) / 4, 256, 0, stream>>>(
        offsB, offsE, csr, (const uint4*)featb3, el3, er3, (uint4*)zb3, mm);
  }

  dim3 wgrid((N_NODES + 63) / 64, N_META);
  w_gemm_mfma<<<wgrid, 256, 0, stream>>>(zb3, w1T, b1, w2, partial, N_NODES);

  reduce_final_kernel<<<N_META, 256, 0, stream>>>(partial, pw, pb, out);
}

// Round 11
// 325.010 us; speedup vs baseline: 1.2361x; 1.2250x over previous
//
#include <hip/hip_runtime.h>

#define N_NODES 50000
#define N_EDGES 800000
#define N_META 3
#define IN_DIM 256
#define HD 128
#define HEADS 8
#define HID 16
#define OUT_DIM 8
#define NBKT 196          // ceil(50000/256) coarse buckets; == #4096-edge tiles
#define BCAP 5120         // padded bucket capacity (mean 4096, +16 sigma)
#define TILE_E 4096       // edges per bin block
#define GEMM_BX ((N_NODES + 63) / 64)           // 782 (gemm half, 64 rows/blk)
#define WG_BX   ((N_NODES + 63) / 64)           // 782 (w_gemm blocks)
#define ELER_BX ((N_NODES * HEADS + 255) / 256) // 1563
#define BING_NB (3 * NBKT)                      // 588 bin blocks (flattened meta)
#define PSTRIDE 132       // per-block partial row: 128 numerator + denom + pad

using bf16x8 = __attribute__((ext_vector_type(8))) short;
using f32x4  = __attribute__((ext_vector_type(4))) float;

__device__ __forceinline__ float bf2f(unsigned short u) {
  union { unsigned int i; float f; } x; x.i = ((unsigned int)u) << 16; return x.f;
}
__device__ __forceinline__ unsigned short f2bf(float f) {
  union { float f; unsigned int i; } x; x.f = f;
  unsigned int r = x.i + 0x7fffu + ((x.i >> 16) & 1u);
  return (unsigned short)(r >> 16);
}
__device__ __forceinline__ float tanh_fast(float x) {
  float e = __expf(2.f * x);
  return 1.f - 2.f / (e + 1.f);
}

// -------- prep: fcw -> fcwT bf16; w1 -> w1T bf16; zero gcur ------------------
__global__ __launch_bounds__(256)
void prep_kernel(const float* __restrict__ fcw, const float* __restrict__ w1,
                 unsigned short* __restrict__ fcwT, unsigned short* __restrict__ w1T,
                 int* __restrict__ gcur) {
  int i = blockIdx.x * 256 + threadIdx.x;
  const int NFC = N_META * IN_DIM * HD;        // 98304
  const int NW1 = HD * HD;                     // 16384
  const int NGC = N_META * NBKT;               // 588
  if (i < NFC) {
    int p = i / (IN_DIM * HD);
    int rem = i - p * (IN_DIM * HD);
    int k = rem / HD, n = rem - k * HD;
    fcwT[(size_t)p * HD * IN_DIM + n * IN_DIM + k] = f2bf(fcw[i]);
  } else if (i < NFC + NW1) {
    int j = i - NFC;
    int k = j / HD, n = j - k * HD;
    w1T[n * HD + k] = f2bf(w1[j]);
  } else if (i < NFC + NW1 + NGC) {
    gcur[i - NFC - NW1] = 0;
  }
}

// ===== Merged dispatch A: bin (x<3*NBKT, meta folded) || gemm_feat ===========
// R23: recompose the measured winners. R15-vs-R19 totals showed the bin/gemm
// split costs ~30-35 us of lost concurrency (bin = LDS-atomic-bound, gemm =
// MFMA/latency-bound; they overlap when co-dispatched). Gemm half is the
// best-measured 48 us N-split body (R17/R19): wave w owns 96 of 384 concat
// cols, 10 ds_read_b128 per 24 MFMA, acc[4][6]. Same 35840 B smem footprint.
__global__ __launch_bounds__(256)
void bin_gemm_kernel(const int* __restrict__ edges, int* __restrict__ gcur,
                     unsigned int* __restrict__ bktbuf,
                     const float* __restrict__ A,
                     const unsigned short* __restrict__ BT,
                     unsigned short* __restrict__ Cb, int nrows) {
  __shared__ char smem[35840];   // gemm: 64*40*2 + 384*40*2; bin: 3*196*4
  int t = threadIdx.x;
  int bx = blockIdx.x;
  if (bx < BING_NB) {
    // ---- bin body: padded-bucket counting-sort pass A ----
    int p = bx / NBKT;
    int b = bx - p * NBKT;
    int* hist  = (int*)smem;
    int* gbase = hist + NBKT;
    int* fill  = gbase + NBKT;
    int e0 = b * TILE_E;
    const int* src = edges + (size_t)p * 2 * N_EDGES;
    const int* dst = src + N_EDGES;
    for (int i = t; i < NBKT; i += 256) { hist[i] = 0; fill[i] = 0; }
    __syncthreads();
    for (int i = t; i < TILE_E; i += 256) {
      int e = e0 + i;
      if (e < N_EDGES) atomicAdd(&hist[dst[e] >> 8], 1);
    }
    __syncthreads();
    for (int i = t; i < NBKT; i += 256) {
      int idx = p * NBKT + i;
      gbase[i] = hist[i] ? (idx * BCAP + atomicAdd(&gcur[idx], hist[i])) : 0;
    }
    __syncthreads();
    for (int i = t; i < TILE_E; i += 256) {
      int e = e0 + i;
      if (e < N_EDGES) {
        int d = dst[e];
        int b2 = d >> 8;
        int r = atomicAdd(&fill[b2], 1);
        bktbuf[gbase[b2] + r] = ((unsigned int)(d & 255) << 16) | (unsigned int)src[e];
      }
    }
  } else {
    // ---- gemm body: featb[m] = bf16(h @ fc_w[m]) for m=0..2, one A-tile ----
    unsigned short* As = (unsigned short*)smem;          // 64*40
    unsigned short* Bs = As + 64 * 40;                   // 384*40 (3 metas)
    int w = t >> 6, l = t & 63, q = l >> 4, s = l & 15;
    int row0 = (bx - BING_NB) * 64;
    f32x4 acc[4][6] = {};
    for (int k0 = 0; k0 < IN_DIM; k0 += 32) {
      {
        int r = t >> 2, c = (t & 3) * 8;
        int gr = row0 + r;
        float4 a0, a1;
        if (gr < nrows) {
          a0 = *(const float4*)(A + (size_t)gr * IN_DIM + k0 + c);
          a1 = *(const float4*)(A + (size_t)gr * IN_DIM + k0 + c + 4);
        } else {
          a0 = make_float4(0.f, 0.f, 0.f, 0.f); a1 = a0;
        }
        ushort4 u0, u1;
        u0.x = f2bf(a0.x); u0.y = f2bf(a0.y); u0.z = f2bf(a0.z); u0.w = f2bf(a0.w);
        u1.x = f2bf(a1.x); u1.y = f2bf(a1.y); u1.z = f2bf(a1.z); u1.w = f2bf(a1.w);
        *(ushort4*)&As[r * 40 + c]     = u0;
        *(ushort4*)&As[r * 40 + c + 4] = u1;
      }
      {
        int n = t >> 1, c = (t & 1) * 16;
        #pragma unroll
        for (int mm = 0; mm < 3; ++mm) {
          const unsigned short* BTm =
              BT + (size_t)mm * HD * IN_DIM + (size_t)n * IN_DIM + k0 + c;
          uint4 b0 = *(const uint4*)(BTm);
          uint4 b1 = *(const uint4*)(BTm + 8);
          unsigned short* Bsm = Bs + (mm * 128 + n) * 40 + c;
          *(uint4*)&Bsm[0] = b0;
          *(uint4*)&Bsm[8] = b1;
        }
      }
      __syncthreads();
      bf16x8 bfv[6];
      #pragma unroll
      for (int nt = 0; nt < 6; ++nt)
        bfv[nt] = *(bf16x8*)&Bs[(w * 96 + nt * 16 + s) * 40 + q * 8];
      #pragma unroll
      for (int mt = 0; mt < 4; ++mt) {
        bf16x8 af = *(bf16x8*)&As[(mt * 16 + s) * 40 + q * 8];
        #pragma unroll
        for (int nt = 0; nt < 6; ++nt)
          acc[mt][nt] = __builtin_amdgcn_mfma_f32_16x16x32_bf16(af, bfv[nt], acc[mt][nt], 0, 0, 0);
      }
      __syncthreads();
    }
    #pragma unroll
    for (int mt = 0; mt < 4; ++mt) {
      #pragma unroll
      for (int nt = 0; nt < 6; ++nt) {
        int gc = w * 96 + nt * 16 + s;
        int mm = gc >> 7, cim = gc & 127;
        unsigned short* Cm = Cb + (size_t)mm * N_NODES * HD;
        #pragma unroll
        for (int r = 0; r < 4; ++r) {
          int gr = row0 + mt * 16 + q * 4 + r;
          if (gr < nrows) Cm[(size_t)gr * HD + cim] = f2bf(acc[mt][nt][r]);
        }
      }
    }
  }
}

// ===== Merged dispatch B: csr_sort (x<NBKT) || el_er (x>=NBKT), y = meta =====
__global__ __launch_bounds__(256)
void sort_eler_kernel(const int* __restrict__ gcur,
                      const unsigned int* __restrict__ bktbuf,
                      int* __restrict__ offsB, int* __restrict__ offsE,
                      int* __restrict__ csr,
                      const unsigned short* __restrict__ featb3,
                      const float* __restrict__ al, const float* __restrict__ ar,
                      float* __restrict__ el3, float* __restrict__ er3) {
  __shared__ int lh[256];
  __shared__ int cur[256];
  __shared__ int wsum[4];
  int p = blockIdx.y;
  int t = threadIdx.x;
  if (blockIdx.x < NBKT) {
    // ---- csr_sort body ----
    int b = blockIdx.x;
    int lane = t & 63, wid = t >> 6;
    int idx = p * NBKT + b;
    int S = idx * BCAP;
    int E = S + gcur[idx];
    int node0 = b * 256;
    int nn = min(256, N_NODES - node0);
    int gi0 = p * N_NODES + node0;
    lh[t] = 0;
    __syncthreads();
    for (int i = S + t; i < E; i += 256) atomicAdd(&lh[bktbuf[i] >> 16], 1);
    __syncthreads();
    int v = lh[t];
    int s = v;
    #pragma unroll
    for (int d = 1; d < 64; d <<= 1) {
      int x = __shfl_up(s, d);
      if (lane >= d) s += x;
    }
    if (lane == 63) wsum[wid] = s;
    __syncthreads();
    int woff = 0;
    #pragma unroll
    for (int k = 0; k < 4; ++k) if (k < wid) woff += wsum[k];
    int excl = S + woff + s - v;
    if (t < nn) {
      offsB[gi0 + t] = excl;
      offsE[gi0 + t] = excl + v;
    }
    cur[t] = excl;
    __syncthreads();
    for (int i = S + t; i < E; i += 256) {
      unsigned int rec = bktbuf[i];
      int pos = atomicAdd(&cur[rec >> 16], 1);
      csr[pos] = (int)(rec & 0xffffu);
    }
  } else {
    // ---- el_er body ----
    int i = (blockIdx.x - NBKT) * 256 + t;
    if (i >= N_NODES * HEADS) return;
    int node = i >> 3, hh = i & 7;
    const unsigned short* f =
        featb3 + (size_t)p * N_NODES * HD + (size_t)node * HD + hh * HID;
    uint4 u0 = *(const uint4*)(f);
    uint4 u1 = *(const uint4*)(f + 8);
    unsigned int uu[8] = {u0.x, u0.y, u0.z, u0.w, u1.x, u1.y, u1.z, u1.w};
    const float* alm = al + p * HD + hh * HID;
    const float* arm = ar + p * HD + hh * HID;
    float sl = 0.f, sr = 0.f;
    #pragma unroll
    for (int q = 0; q < 8; ++q) {
      float v0 = __uint_as_float(uu[q] << 16);
      float v1 = __uint_as_float(uu[q] & 0xffff0000u);
      int d = q * 2;
      sl += v0 * alm[d] + v1 * alm[d + 1];
      sr += v0 * arm[d] + v1 * arm[d + 1];
    }
    el3[(size_t)p * N_NODES * HEADS + i] = sl;
    er3[(size_t)p * N_NODES * HEADS + i] = sr;
  }
}

// ------- GAT aggregation (y = meta; at gather-path roofline) -----------------
__global__ __launch_bounds__(256)
void aggregate_kernel(const int* __restrict__ offsB3, const int* __restrict__ offsE3,
                      const int* __restrict__ csr,
                      const uint4* __restrict__ featb3_u4,
                      const float* __restrict__ el3, const float* __restrict__ er3,
                      uint4* __restrict__ zb3_u4) {
  int m = blockIdx.y;
  int node = blockIdx.x * 4 + (threadIdx.x >> 6);
  if (node >= N_NODES) return;
  const uint4* featb_u4 = featb3_u4 + (size_t)m * N_NODES * 16;
  const float* el = el3 + (size_t)m * N_NODES * HEADS;
  const float* er = er3 + (size_t)m * N_NODES * HEADS;
  uint4* z_u4 = zb3_u4 + (size_t)m * N_NODES * 16;
  int lane = threadIdx.x & 63;
  int qg = lane >> 4;                // edge sub-slot base (0..3)
  int li = lane & 15;                // column quad (cols 8li..8li+7)
  int ch = li >> 1;                  // head of those columns
  int beg = offsB3[m * N_NODES + node], end = offsE3[m * N_NODES + node];
  float erh = er[node * HEADS + ch];
  float ssum = 0.f;
  float a[8] = {};
  for (int i = beg; i < end; i += 16) {
    int nk = end - i;
    int last = end - 1;
    int s0 = csr[min(i + qg,      last)];
    int s1 = csr[min(i + qg + 4,  last)];
    int s2 = csr[min(i + qg + 8,  last)];
    int s3 = csr[min(i + qg + 12, last)];
    uint4 v0 = featb_u4[(size_t)s0 * 16 + li];
    uint4 v1 = featb_u4[(size_t)s1 * 16 + li];
    uint4 v2 = featb_u4[(size_t)s2 * 16 + li];
    uint4 v3 = featb_u4[(size_t)s3 * 16 + li];
    float e0 = el[s0 * HEADS + ch] + erh;
    float e1 = el[s1 * HEADS + ch] + erh;
    float e2 = el[s2 * HEADS + ch] + erh;
    float e3 = el[s3 * HEADS + ch] + erh;
    e0 = e0 > 0.f ? e0 : 0.2f * e0;
    e1 = e1 > 0.f ? e1 : 0.2f * e1;
    e2 = e2 > 0.f ? e2 : 0.2f * e2;
    e3 = e3 > 0.f ? e3 : 0.2f * e3;
    float w0 = (qg      < nk) ? __expf(e0) : 0.f;
    float w1 = (qg + 4  < nk) ? __expf(e1) : 0.f;
    float w2 = (qg + 8  < nk) ? __expf(e2) : 0.f;
    float w3 = (qg + 12 < nk) ? __expf(e3) : 0.f;
    ssum += (w0 + w1) + (w2 + w3);
    a[0] += w0 * __uint_as_float(v0.x << 16);
    a[1] += w0 * __uint_as_float(v0.x & 0xffff0000u);
    a[2] += w0 * __uint_as_float(v0.y << 16);
    a[3] += w0 * __uint_as_float(v0.y & 0xffff0000u);
    a[4] += w0 * __uint_as_float(v0.z << 16);
    a[5] += w0 * __uint_as_float(v0.z & 0xffff0000u);
    a[6] += w0 * __uint_as_float(v0.w << 16);
    a[7] += w0 * __uint_as_float(v0.w & 0xffff0000u);
    a[0] += w1 * __uint_as_float(v1.x << 16);
    a[1] += w1 * __uint_as_float(v1.x & 0xffff0000u);
    a[2] += w1 * __uint_as_float(v1.y << 16);
    a[3] += w1 * __uint_as_float(v1.y & 0xffff0000u);
    a[4] += w1 * __uint_as_float(v1.z << 16);
    a[5] += w1 * __uint_as_float(v1.z & 0xffff0000u);
    a[6] += w1 * __uint_as_float(v1.w << 16);
    a[7] += w1 * __uint_as_float(v1.w & 0xffff0000u);
    a[0] += w2 * __uint_as_float(v2.x << 16);
    a[1] += w2 * __uint_as_float(v2.x & 0xffff0000u);
    a[2] += w2 * __uint_as_float(v2.y << 16);
    a[3] += w2 * __uint_as_float(v2.y & 0xffff0000u);
    a[4] += w2 * __uint_as_float(v2.z << 16);
    a[5] += w2 * __uint_as_float(v2.z & 0xffff0000u);
    a[6] += w2 * __uint_as_float(v2.w << 16);
    a[7] += w2 * __uint_as_float(v2.w & 0xffff0000u);
    a[0] += w3 * __uint_as_float(v3.x << 16);
    a[1] += w3 * __uint_as_float(v3.x & 0xffff0000u);
    a[2] += w3 * __uint_as_float(v3.y << 16);
    a[3] += w3 * __uint_as_float(v3.y & 0xffff0000u);
    a[4] += w3 * __uint_as_float(v3.z << 16);
    a[5] += w3 * __uint_as_float(v3.z & 0xffff0000u);
    a[6] += w3 * __uint_as_float(v3.w << 16);
    a[7] += w3 * __uint_as_float(v3.w & 0xffff0000u);
  }
  #pragma unroll
  for (int j = 0; j < 8; ++j) {
    a[j] += __shfl_xor(a[j], 16);
    a[j] += __shfl_xor(a[j], 32);
  }
  ssum += __shfl_xor(ssum, 16);
  ssum += __shfl_xor(ssum, 32);
  float inv = (end > beg) ? 1.f / ssum : 0.f;
  if (qg == 0) {
    #pragma unroll
    for (int j = 0; j < 8; ++j) {
      float z = a[j] * inv;
      a[j] = z > 0.f ? z : __expf(z) - 1.f;   // fast elu
    }
    uint4 o;
    unsigned int p0, p1, p2, p3;
    asm("v_cvt_pk_bf16_f32 %0, %1, %2" : "=v"(p0) : "v"(a[0]), "v"(a[1]));
    asm("v_cvt_pk_bf16_f32 %0, %1, %2" : "=v"(p1) : "v"(a[2]), "v"(a[3]));
    asm("v_cvt_pk_bf16_f32 %0, %1, %2" : "=v"(p2) : "v"(a[4]), "v"(a[5]));
    asm("v_cvt_pk_bf16_f32 %0, %1, %2" : "=v"(p3) : "v"(a[6]), "v"(a[7]));
    o.x = p0; o.y = p1; o.z = p2; o.w = p3;
    z_u4[(size_t)node * 16 + li] = o;
  }
}

// ------ w_gemm: atomic-free epilogue -> per-block partial rows ---------------
__global__ __launch_bounds__(256)
void w_gemm_mfma(const unsigned short* __restrict__ Zb3,   // [3][N,128] bf16
                 const unsigned short* __restrict__ BT,    // w1T [128][128] bf16
                 const float* __restrict__ B1, const float* __restrict__ W2,
                 float* __restrict__ partial, int nrows) {
  __shared__ unsigned short Bs[128 * 128];   // 32768 B, swizzled 16B chunks
  __shared__ float ew[64];
  __shared__ float part[4][64][2];
  int tid = threadIdx.x;
  int m = blockIdx.y;
  const unsigned short* Zb = Zb3 + (size_t)m * N_NODES * HD;
  int w = tid >> 6, l = tid & 63, q = l >> 4, s = l & 15;
  int row0 = blockIdx.x * 64;
  // stage w1T: chunk j (8 shorts) of row n stored at chunk j^(n&15)
  {
    int n = tid >> 1;
    int jb = (tid & 1) * 8;
    #pragma unroll
    for (int jj = 0; jj < 8; ++jj) {
      int j = jb + jj;
      *(uint4*)&Bs[n * 128 + ((j ^ (n & 15)) << 3)] =
          *(const uint4*)(BT + n * HD + j * 8);
    }
  }
  float b1v[8], w2v[8];
  #pragma unroll
  for (int f = 0; f < 8; ++f) { b1v[f] = B1[f * 16 + s]; w2v[f] = W2[f * 16 + s]; }
  // A fragments direct from global (row clamped; clamped rows' results unused)
  int gra = min(row0 + w * 16 + s, nrows - 1);
  const unsigned short* arow = Zb + (size_t)gra * HD;
  bf16x8 af[4];
  #pragma unroll
  for (int kc = 0; kc < 4; ++kc)
    af[kc] = *(const bf16x8*)(arow + kc * 32 + q * 8);
  __syncthreads();
  f32x4 acc[8] = {};
  #pragma unroll
  for (int kc = 0; kc < 4; ++kc) {
    #pragma unroll
    for (int f = 0; f < 8; ++f) {
      bf16x8 bf = *(bf16x8*)&Bs[(f * 16 + s) * 128 + ((((kc << 2) | q) ^ s) << 3)];
      acc[f] = __builtin_amdgcn_mfma_f32_16x16x32_bf16(af[kc], bf, acc[f], 0, 0, 0);
    }
  }
  // tanh/w2 + s-reduce; lane s==0 writes ew[row] = exp(w-score) (0 if invalid)
  #pragma unroll
  for (int r = 0; r < 4; ++r) {
    float p = 0.f;
    #pragma unroll
    for (int f = 0; f < 8; ++f) p += tanh_fast(acc[f][r] + b1v[f]) * w2v[f];
    p += __shfl_xor(p, 1); p += __shfl_xor(p, 2);
    p += __shfl_xor(p, 4); p += __shfl_xor(p, 8);
    if (s == 0) {
      int rr = w * 16 + q * 4 + r;
      ew[rr] = (row0 + rr < nrows) ? __expf(p) : 0.f;
    }
  }
  __syncthreads();
  // phase 2: numerator cols (2l,2l+1) += ew[r] * z[row0+r][cols], r = w..63(4)
  const unsigned int* Zu = (const unsigned int*)Zb;
  int rmax = min(64, nrows - row0);
  float a0 = 0.f, a1 = 0.f;
  for (int r = w; r < rmax; r += 4) {
    float e = ew[r];
    unsigned int v = Zu[(size_t)(row0 + r) * 64 + l];
    a0 += e * __uint_as_float(v << 16);
    a1 += e * __uint_as_float(v & 0xffff0000u);
  }
  part[w][l][0] = a0;
  part[w][l][1] = a1;
  __syncthreads();
  if (w == 0) {
    float s0 = part[0][l][0] + part[1][l][0] + part[2][l][0] + part[3][l][0];
    float s1 = part[0][l][1] + part[1][l][1] + part[2][l][1] + part[3][l][1];
    float* prow = partial + ((size_t)m * WG_BX + blockIdx.x) * PSTRIDE;
    prow[2 * l]     = s0;
    prow[2 * l + 1] = s1;
    float ldv = ew[l];
    ldv += __shfl_xor(ldv, 1);  ldv += __shfl_xor(ldv, 2);
    ldv += __shfl_xor(ldv, 4);  ldv += __shfl_xor(ldv, 8);
    ldv += __shfl_xor(ldv, 16); ldv += __shfl_xor(ldv, 32);
    if (l == 0) prow[128] = ldv;
  }
}

// ------- reduce partials (782/meta) + final projection -----------------------
__global__ __launch_bounds__(256)
void reduce_final_kernel(const float* __restrict__ partial,
                         const float* __restrict__ PW, const float* __restrict__ PB,
                         float* __restrict__ out) {
  __shared__ float num[129];
  int m = blockIdx.x;
  int t = threadIdx.x;
  if (t < 129) {
    const float* base = partial + (size_t)m * WG_BX * PSTRIDE + t;
    float a0 = 0.f, a1 = 0.f, a2 = 0.f, a3 = 0.f;
    int b = 0;
    for (; b + 4 <= WG_BX; b += 4) {
      a0 += base[(size_t)(b + 0) * PSTRIDE];
      a1 += base[(size_t)(b + 1) * PSTRIDE];
      a2 += base[(size_t)(b + 2) * PSTRIDE];
      a3 += base[(size_t)(b + 3) * PSTRIDE];
    }
    for (; b < WG_BX; ++b) a0 += base[(size_t)b * PSTRIDE];
    num[t] = (a0 + a1) + (a2 + a3);
  }
  __syncthreads();
  if (t < OUT_DIM) {
    float inv = 1.f / num[128];
    float s = 0.f;
    for (int k = 0; k < HD; ++k) s += num[k] * PW[k * OUT_DIM + t];
    out[m * OUT_DIM + t] = s * inv + PB[t];
  }
}

extern "C" void kernel_launch(void* const* d_in, const int* in_sizes, int n_in,
                              void* d_out, int out_size, void* d_ws, size_t ws_size,
                              hipStream_t stream) {
  (void)in_sizes; (void)n_in; (void)out_size; (void)ws_size;
  const float* h     = (const float*)d_in[0];
  const int*   edges = (const int*)d_in[1];
  const float* fcw   = (const float*)d_in[2];
  const float* al    = (const float*)d_in[3];
  const float* ar    = (const float*)d_in[4];
  const float* w1    = (const float*)d_in[5];
  const float* b1    = (const float*)d_in[6];
  const float* w2    = (const float*)d_in[7];
  const float* pw    = (const float*)d_in[8];
  const float* pb    = (const float*)d_in[9];
  float* out = (float*)d_out;

  char* ws = (char*)d_ws;
  size_t off = 0;
  auto alloc = [&](size_t bytes) -> void* {
    void* p = ws + off;
    off = (off + bytes + 255) & ~(size_t)255;
    return p;
  };
  unsigned short* featb3 = (unsigned short*)alloc((size_t)N_META * N_NODES * HD * 2);
  unsigned short* zb3    = (unsigned short*)alloc((size_t)N_META * N_NODES * HD * 2);
  unsigned short* fcwT   = (unsigned short*)alloc((size_t)N_META * HD * IN_DIM * 2);
  unsigned short* w1T    = (unsigned short*)alloc((size_t)HD * HD * 2);
  float* el3 = (float*)alloc((size_t)N_META * N_NODES * HEADS * 4);
  float* er3 = (float*)alloc((size_t)N_META * N_NODES * HEADS * 4);
  int* gcur  = (int*)alloc((size_t)N_META * NBKT * 4);
  int* offsB = (int*)alloc((size_t)N_META * N_NODES * 4);
  int* offsE = (int*)alloc((size_t)N_META * N_NODES * 4);
  unsigned int* bktbuf = (unsigned int*)alloc((size_t)N_META * NBKT * BCAP * 4);
  int* csr   = (int*)alloc((size_t)N_META * NBKT * BCAP * 4);
  float* partial = (float*)alloc((size_t)N_META * WG_BX * PSTRIDE * 4);

  const int PREP_N = N_META * IN_DIM * HD + HD * HD + N_META * NBKT;
  prep_kernel<<<(PREP_N + 255) / 256, 256, 0, stream>>>(
      fcw, w1, fcwT, w1T, gcur);

  // A: bin (meta-flattened) || gemm_feat (N-split, all 3 metas) — overlapped
  bin_gemm_kernel<<<BING_NB + GEMM_BX, 256, 0, stream>>>(
      edges, gcur, bktbuf, h, fcwT, featb3, N_NODES);

  // B: csr_sort || el_er (independent halves)
  dim3 bgrid_(NBKT + ELER_BX, N_META);
  sort_eler_kernel<<<bgrid_, 256, 0, stream>>>(
      gcur, bktbuf, offsB, offsE, csr, featb3, al, ar, el3, er3);

  // aggregate: single dispatch, y = meta (less tail than 3 serial launches)
  dim3 ggrid((N_NODES + 3) / 4, N_META);
  aggregate_kernel<<<ggrid, 256, 0, stream>>>(
      offsB, offsE, csr, (const uint4*)featb3, el3, er3, (uint4*)zb3);

  dim3 wgrid((N_NODES + 63) / 64, N_META);
  w_gemm_mfma<<<wgrid, 256, 0, stream>>>(zb3, w1T, b1, w2, partial, N_NODES);

  reduce_final_kernel<<<N_META, 256, 0, stream>>>(partial, pw, pb, out);
}